// Round 3
// baseline (32.400 us; speedup 1.0000x reference)
//
#include <hip/hip_runtime.h>
#include <hip/hip_bf16.h>

// Cost volume: cost[b,i,h,w] = mean_c f1[b,c,h,w] * f2[b,c,h,w-i], i in [0,64), 0 if w<i.
// Shapes: B=4, C=128, H=128, W=256, lvls=64. fp32 in/out, bf16 MFMA compute.
//
// One workgroup (512 thr, 8 waves) per (b,h). Banded Gram via 32x32x16 bf16 MFMA,
// wave j owns w-tile [32j,32j+32) and 3 p-tiles (clamped branch-free).
//
// R3 change: K-slabs of f1/f2 ([16 c][256 w] fp32, 16 KiB each) are staged into
// double-buffered LDS with global_load_lds width=16 (1 KiB per wave-instruction,
// 4 instr/wave/k-step issued BEFORE computing the current buffer). This keeps
// ~32 KB/block of loads in flight (Little's law fix for the latency bound).
// Fragment reads are ds_read_b32 at bank = w%32 -> conflict-free.
// Epilogue [i][w] transpose buffer aliases the staging LDS (barrier-separated).

#define BDIM 4
#define CDIM 128
#define HDIM 128
#define WDIM 256
#define LVLS 64
#define HW   (HDIM * WDIM)          // 32768
#define CHW  (CDIM * HDIM * WDIM)   // 4194304

typedef short  bf16x8 __attribute__((ext_vector_type(8)));
typedef float  f32x16 __attribute__((ext_vector_type(16)));

typedef __attribute__((address_space(1))) const unsigned int guint;
typedef __attribute__((address_space(3))) unsigned int luint;

__device__ __forceinline__ short f2bf(float f) {
    __hip_bfloat16 h = __float2bfloat16(f);
    return __builtin_bit_cast(short, h);
}

__global__ __launch_bounds__(512, 4) void cost_volume_kernel(
    const float* __restrict__ f1, const float* __restrict__ f2,
    float* __restrict__ out)
{
    // 64 KiB: staging double buffer (2 x {f1 slab 4096 f32, f2 slab 4096 f32}),
    // reused as cost[64][256] fp32 for the store-transpose epilogue.
    __shared__ float lds[16384];

    const int tid  = threadIdx.x;
    const int lane = tid & 63;
    const int wv   = tid >> 6;          // wave id 0..7
    const int wg   = blockIdx.x;        // 0..511
    const int b    = wg >> 7;
    const int h    = wg & (HDIM - 1);

    const float* __restrict__ f1bh = f1 + (size_t)b * CHW + (size_t)h * WDIM;
    const float* __restrict__ f2bh = f2 + (size_t)b * CHW + (size_t)h * WDIM;

    const int wl    = lane & 31;            // tile column 0..31
    const int wglob = wv * 32 + wl;         // this lane's output w
    const int koff  = (lane >> 5) * 8;      // k offset within K=16 step

    // Tiles t=0..2 -> true tp = wv-2+t; clamp (<0 computed on valid addr, discarded).
    const int tp0c = (wv - 2 < 0) ? 0 : wv - 2;
    const int tp1c = (wv - 1 < 0) ? 0 : wv - 1;
    const int c0 = tp0c * 32 + wl;
    const int c1 = tp1c * 32 + wl;
    const int c2 = wv * 32 + wl;

    f32x16 acc0 = (f32x16)0.0f, acc1 = (f32x16)0.0f, acc2 = (f32x16)0.0f;

    // ---- staging: wave wv loads rows {2wv, 2wv+1} of each matrix's k-slab ----
    const int r0 = wv * 2;
    #define STAGE(bb, kk)                                                        \
        do {                                                                     \
            _Pragma("unroll")                                                    \
            for (int rr = 0; rr < 2; ++rr) {                                     \
                const int r = r0 + rr;                                           \
                const float* g1 = f1bh + (size_t)((kk) * 16 + r) * HW + lane * 4;\
                const float* g2 = f2bh + (size_t)((kk) * 16 + r) * HW + lane * 4;\
                float* l1 = &lds[(bb) * 8192 + r * 256];                         \
                float* l2 = &lds[(bb) * 8192 + 4096 + r * 256];                  \
                __builtin_amdgcn_global_load_lds((guint*)g1, (luint*)l1, 16, 0, 0);\
                __builtin_amdgcn_global_load_lds((guint*)g2, (luint*)l2, 16, 0, 0);\
            }                                                                    \
        } while (0)

    STAGE(0, 0);
    __syncthreads();   // drains vmcnt -> buf0 ready

    #pragma unroll
    for (int kk = 0; kk < 8; ++kk) {
        const int bb = kk & 1;
        if (kk < 7) STAGE(bb ^ 1, kk + 1);   // prefetch next slab (in flight during compute)

        const float* L1 = &lds[bb * 8192];
        const float* L2 = &lds[bb * 8192 + 4096];

        bf16x8 fb, fa0, fa1, fa2;
        #pragma unroll
        for (int j = 0; j < 8; ++j) {
            const int k = koff + j;
            fb[j]  = f2bf(L1[k * 256 + wglob]);
            fa0[j] = f2bf(L2[k * 256 + c0]);
            fa1[j] = f2bf(L2[k * 256 + c1]);
            fa2[j] = f2bf(L2[k * 256 + c2]);
        }

        acc0 = __builtin_amdgcn_mfma_f32_32x32x16_bf16(fa0, fb, acc0, 0, 0, 0);
        acc1 = __builtin_amdgcn_mfma_f32_32x32x16_bf16(fa1, fb, acc1, 0, 0, 0);
        acc2 = __builtin_amdgcn_mfma_f32_32x32x16_bf16(fa2, fb, acc2, 0, 0, 0);

        __syncthreads();   // next iter overwrites buf bb^1's predecessor + drains its loads
    }

    // ---- Epilogue: acc tiles -> LDS [i][w] (aliases staging bufs), coalesced store ----

    float* cost_lds = lds;

    // zero-fill triangle i > w (only w<64, i.e. waves 0,1)
    if (wv < 2 && lane < 32) {
        #pragma unroll 1
        for (int i = 1; i < LVLS; ++i)
            if (i > wglob) cost_lds[i * WDIM + wglob] = 0.0f;
    }

    // scatter: D row = (r&3) + 8*(r>>2) + 4*(lane>>5), col = lane&31
    const int rbase = 4 * (lane >> 5);
    {
        const f32x16* accs[3] = { &acc0, &acc1, &acc2 };
        #pragma unroll
        for (int t = 0; t < 3; ++t) {
            const int tp = wv - 2 + t;
            if (tp >= 0) {
                const f32x16 a = *accs[t];
                #pragma unroll
                for (int r = 0; r < 16; ++r) {
                    const int prow = tp * 32 + (r & 3) + 8 * (r >> 2) + rbase;
                    const int i = wglob - prow;   // disparity
                    if (i >= 0 && i < LVLS)
                        cost_lds[i * WDIM + wglob] = a[r] * (1.0f / CDIM);
                }
            }
        }
    }

    __syncthreads();

    // coalesced store: out[b][i][h][w]; LDS row i contiguous <-> global row i contiguous
    const size_t obase = ((size_t)b * LVLS) * HW + (size_t)h * WDIM;
    #pragma unroll
    for (int rep = 0; rep < 8; ++rep) {
        const int idx = rep * 512 + tid;      // 0..4095 float4s
        const int row = idx >> 6;             // i
        const int w4  = idx & 63;
        const float4 v = *reinterpret_cast<const float4*>(&cost_lds[row * WDIM + w4 * 4]);
        *reinterpret_cast<float4*>(out + obase + (size_t)row * HW + w4 * 4) = v;
    }
}

extern "C" void kernel_launch(void* const* d_in, const int* in_sizes, int n_in,
                              void* d_out, int out_size, void* d_ws, size_t ws_size,
                              hipStream_t stream) {
    const float* f1 = (const float*)d_in[0];
    const float* f2 = (const float*)d_in[1];
    float* out = (float*)d_out;
    cost_volume_kernel<<<dim3(BDIM * HDIM), dim3(512), 0, stream>>>(f1, f2, out);
}

// Round 5
// 31.460 us; speedup vs baseline: 1.0299x; 1.0299x over previous
//
#include <hip/hip_runtime.h>
#include <hip/hip_bf16.h>

// Cost volume: cost[b,i,h,w] = mean_c f1[b,c,h,w] * f2[b,c,h,w-i], i in [0,64), 0 if w<i.
// B=4, C=128, H=128, W=256, lvls=64. fp32 in/out, bf16 MFMA compute.
//
// One workgroup (512 thr, 8 waves) per (b,h). Banded Gram via 32x32x16 bf16 MFMA.
// R4/R5: T14 reg-staged pipeline. Global->reg (float4) -> cvt_pk bf16 -> ds_write_b128,
// 2 slabs of global loads in flight across RAW s_barriers (no vmcnt drain).
// LDS slabs hold packed bf16 pairs [kp][w] (word = {k=2kp lo16, k=2kp+1 hi16}),
// so fragment reads are 4x ds_read_b32/frag, conflict-free. Output via LDS [i][w]
// transpose, nontemporal float4 stores (keep inputs LLC-resident).
// R5 fix: nontemporal store needs a NATIVE clang vector type, not HIP float4.

#define BDIM 4
#define CDIM 128
#define HDIM 128
#define WDIM 256
#define LVLS 64
#define HW   (HDIM * WDIM)          // 32768
#define CHW  (CDIM * HDIM * WDIM)   // 4194304

typedef short    bf16x8 __attribute__((ext_vector_type(8)));
typedef float    f32x16 __attribute__((ext_vector_type(16)));
typedef float    f32x4  __attribute__((ext_vector_type(4)));
typedef unsigned u32x4  __attribute__((ext_vector_type(4)));

__device__ __forceinline__ unsigned packbf(float lo, float hi) {
    unsigned a = (unsigned)(unsigned short)__builtin_bit_cast(unsigned short, __float2bfloat16(lo));
    unsigned b = (unsigned)(unsigned short)__builtin_bit_cast(unsigned short, __float2bfloat16(hi));
    return a | (b << 16);
}

__global__ __launch_bounds__(512, 4) void cost_volume_kernel(
    const float* __restrict__ f1, const float* __restrict__ f2,
    float* __restrict__ out)
{
    // 64 KiB, aliased: staging = 2 bufs x {f1 8KB, f2 8KB} packed bf16 (32 KiB);
    // epilogue = cost[64][256] fp32 (64 KiB).
    __shared__ __align__(16) char lds_raw[65536];
    unsigned* stage = (unsigned*)lds_raw;          // word idx: buf*4096 + mat*2048 + kp*256 + w
    float*    cost  = (float*)lds_raw;

    const int tid  = threadIdx.x;
    const int lane = tid & 63;
    const int wv   = tid >> 6;          // wave 0..7
    const int wg   = blockIdx.x;        // 0..511
    const int b    = wg >> 7;
    const int h    = wg & (HDIM - 1);

    const float* __restrict__ f1bh = f1 + (size_t)b * CHW + (size_t)h * WDIM;
    const float* __restrict__ f2bh = f2 + (size_t)b * CHW + (size_t)h * WDIM;

    const int wl    = lane & 31;
    const int wglob = wv * 32 + wl;
    const int krow  = (lane >> 5) * 4;  // word-row offset of this half-wave's k range

    // p-tiles t=0..2 -> tp = wv-2+t, clamped (invalid computed on valid addr, discarded)
    const int c0 = ((wv - 2 < 0) ? 0 : wv - 2) * 32 + wl;
    const int c1 = ((wv - 1 < 0) ? 0 : wv - 1) * 32 + wl;
    const int c2 = wv * 32 + wl;

    f32x16 acc0 = (f32x16)0.0f, acc1 = (f32x16)0.0f, acc2 = (f32x16)0.0f;

    // Per slab s: wave wv stages k-pair row kp=wv (global rows s*16+2wv, +2wv+1),
    // lane covers w = lane*4 .. lane*4+3. Two register sets (s&1).
    f32x4 L1a[2], L1b[2], L2a[2], L2b[2];

    #define ISSUE(s) do {                                                          \
        const float* g1 = f1bh + (size_t)((s) * 16 + 2 * wv) * HW + lane * 4;      \
        const float* g2 = f2bh + (size_t)((s) * 16 + 2 * wv) * HW + lane * 4;      \
        L1a[(s) & 1] = *(const f32x4*)g1; L1b[(s) & 1] = *(const f32x4*)(g1 + HW); \
        L2a[(s) & 1] = *(const f32x4*)g2; L2b[(s) & 1] = *(const f32x4*)(g2 + HW); \
    } while (0)

    #define WRITE(s) do {                                                          \
        const int bb_ = (s) & 1;                                                   \
        unsigned* p1 = stage + bb_ * 4096 + wv * 256 + (lane << 2);                \
        u32x4 w1 = { packbf(L1a[bb_].x, L1b[bb_].x), packbf(L1a[bb_].y, L1b[bb_].y),\
                     packbf(L1a[bb_].z, L1b[bb_].z), packbf(L1a[bb_].w, L1b[bb_].w) };\
        *(u32x4*)p1 = w1;                                                          \
        u32x4 w2 = { packbf(L2a[bb_].x, L2b[bb_].x), packbf(L2a[bb_].y, L2b[bb_].y),\
                     packbf(L2a[bb_].z, L2b[bb_].z), packbf(L2a[bb_].w, L2b[bb_].w) };\
        *(u32x4*)(p1 + 2048) = w2;                                                 \
    } while (0)

    // ---- prologue: fill pipeline (2 slabs of loads in flight) ----
    ISSUE(0); ISSUE(1);
    WRITE(0);            // compiler waits slab0's loads only (slab1 stays in flight)
    ISSUE(2);
    asm volatile("s_waitcnt lgkmcnt(0)" ::: "memory");
    __builtin_amdgcn_sched_barrier(0);
    __builtin_amdgcn_s_barrier();      // raw: does NOT drain vmcnt
    __builtin_amdgcn_sched_barrier(0);

    // ---- K loop: 8 slabs of K=16 ----
    #pragma unroll
    for (int kk = 0; kk < 8; ++kk) {
        if (kk < 7) WRITE(kk + 1);                 // cvt+write next slab (waits its loads)
        if (kk + 3 <= 7) ISSUE(kk + 3);            // keep 2 slabs of loads flying

        const int bb = kk & 1;
        const unsigned* sb = stage + bb * 4096;
        u32x4 wb, wa0, wa1, wa2;
        #pragma unroll
        for (int d = 0; d < 4; ++d) {
            wb[d]  = sb[(krow + d) * 256 + wglob];
            wa0[d] = sb[2048 + (krow + d) * 256 + c0];
            wa1[d] = sb[2048 + (krow + d) * 256 + c1];
            wa2[d] = sb[2048 + (krow + d) * 256 + c2];
        }
        asm volatile("s_waitcnt lgkmcnt(0)" ::: "memory");
        __builtin_amdgcn_sched_barrier(0);

        const bf16x8 fb  = __builtin_bit_cast(bf16x8, wb);
        const bf16x8 fa0 = __builtin_bit_cast(bf16x8, wa0);
        const bf16x8 fa1 = __builtin_bit_cast(bf16x8, wa1);
        const bf16x8 fa2 = __builtin_bit_cast(bf16x8, wa2);
        acc0 = __builtin_amdgcn_mfma_f32_32x32x16_bf16(fa0, fb, acc0, 0, 0, 0);
        acc1 = __builtin_amdgcn_mfma_f32_32x32x16_bf16(fa1, fb, acc1, 0, 0, 0);
        acc2 = __builtin_amdgcn_mfma_f32_32x32x16_bf16(fa2, fb, acc2, 0, 0, 0);

        if (kk < 7) {
            __builtin_amdgcn_sched_barrier(0);
            __builtin_amdgcn_s_barrier();          // raw: loads for kk+2/kk+3 stay in flight
            __builtin_amdgcn_sched_barrier(0);
        }
    }

    #undef ISSUE
    #undef WRITE

    // ---- Epilogue: acc -> LDS [i][w] transpose, nontemporal coalesced store ----
    __syncthreads();   // staging fully consumed; safe to overwrite as cost[]

    // zero-fill triangle i > w (only w < 64, i.e. waves 0,1)
    if (wv < 2 && lane < 32) {
        #pragma unroll 1
        for (int i = 1; i < LVLS; ++i)
            if (i > wglob) cost[i * WDIM + wglob] = 0.0f;
    }

    // scatter: D row = (r&3) + 8*(r>>2) + 4*(lane>>5), col = lane&31
    const int rbase = 4 * (lane >> 5);
    {
        const f32x16* accs[3] = { &acc0, &acc1, &acc2 };
        #pragma unroll
        for (int t = 0; t < 3; ++t) {
            const int tp = wv - 2 + t;
            if (tp >= 0) {
                const f32x16 a = *accs[t];
                #pragma unroll
                for (int r = 0; r < 16; ++r) {
                    const int prow = tp * 32 + (r & 3) + 8 * (r >> 2) + rbase;
                    const int i = wglob - prow;
                    if (i >= 0 && i < LVLS)
                        cost[i * WDIM + wglob] = a[r] * (1.0f / CDIM);
                }
            }
        }
    }

    __syncthreads();

    const size_t obase = ((size_t)b * LVLS) * HW + (size_t)h * WDIM;
    #pragma unroll
    for (int rep = 0; rep < 8; ++rep) {
        const int idx = rep * 512 + tid;      // 0..4095 float4s
        const int row = idx >> 6;             // i
        const int w4  = idx & 63;
        const f32x4 v = *reinterpret_cast<const f32x4*>(&cost[row * WDIM + w4 * 4]);
        __builtin_nontemporal_store(v, reinterpret_cast<f32x4*>(out + obase + (size_t)row * HW + w4 * 4));
    }
}

extern "C" void kernel_launch(void* const* d_in, const int* in_sizes, int n_in,
                              void* d_out, int out_size, void* d_ws, size_t ws_size,
                              hipStream_t stream) {
    const float* f1 = (const float*)d_in[0];
    const float* f2 = (const float*)d_in[1];
    float* out = (float*)d_out;
    cost_volume_kernel<<<dim3(BDIM * HDIM), dim3(512), 0, stream>>>(f1, f2, out);
}

// Round 8
// 30.462 us; speedup vs baseline: 1.0636x; 1.0328x over previous
//
#include <hip/hip_runtime.h>
#include <hip/hip_bf16.h>

// Cost volume: cost[b,i,h,w] = mean_c f1[b,c,h,w] * f2[b,c,h,w-i], i in [0,64), 0 if w<i.
// B=4, C=128, H=128, W=256, lvls=64. fp32 in/out, bf16 MFMA compute.
//
// R8: desynchronized single-wave blocks (R7) + explicit LDS fences.
// One WAVE per work unit (b, h, wt), wt = 32-wide w-tile: grid 4096 x 64 thr.
//   - 3 band p-tiles via 32x32x16 bf16 MFMA, K=128 fully unrolled,
//     direct global scalar loads (branch-free, clamped invalid tiles),
//   - private 8 KiB LDS strip [64 i][32 w] transpose, nontemporal stores.
// R8 fix: R7's post-timing divergence = dynamic LDS RAW hazard. The strip is
// written as scalar float (scatter) and read as f32x4 (store loop); TBAA says
// these don't alias, so the compiler may omit the lgkmcnt wait between the
// ds_write and the ds_read_b128 -> timing-dependent stale reads under replay.
// Every passing version had __syncthreads() (fence + lgkmcnt drain) there.
// Fix: explicit s_waitcnt lgkmcnt(0) + sched_barrier at both LDS phase
// boundaries (zero->scatter, scatter->read). No cross-wave barriers added.

#define BDIM 4
#define CDIM 128
#define HDIM 128
#define WDIM 256
#define LVLS 64
#define HW   (HDIM * WDIM)          // 32768
#define CHW  (CDIM * HDIM * WDIM)   // 4194304
#define NWORK (BDIM * HDIM * 8)     // 4096 work units

typedef short    bf16x8 __attribute__((ext_vector_type(8)));
typedef float    f32x16 __attribute__((ext_vector_type(16)));
typedef float    f32x4  __attribute__((ext_vector_type(4)));

__device__ __forceinline__ short f2bf(float f) {
    __hip_bfloat16 h = __float2bfloat16(f);
    return __builtin_bit_cast(short, h);
}

__device__ __forceinline__ void lds_fence() {
    // order LDS phases within the wave: drain outstanding DS ops and pin the
    // compiler's schedule across the boundary (TBAA can't see the aliasing).
    asm volatile("s_waitcnt lgkmcnt(0)" ::: "memory");
    __builtin_amdgcn_sched_barrier(0);
}

__global__ __launch_bounds__(64, 4) void cost_volume_kernel(
    const float* __restrict__ f1, const float* __restrict__ f2,
    float* __restrict__ out)
{
    __shared__ float strip[LVLS * 32];   // 8 KiB, private to this single-wave block

    const int lane = threadIdx.x;        // 0..63

    // chunked XCD swizzle (4096 blocks, 8 XCDs, 512-unit chunks): consecutive
    // (h, wt) units (sharing f2 tiles) co-reside on one XCD's L2.
    const int bid  = blockIdx.x;
    const int work = (bid & 7) * (NWORK / 8) + (bid >> 3);

    const int wt = work & 7;             // w-tile 0..7
    const int h  = (work >> 3) & (HDIM - 1);
    const int b  = work >> 10;           // 0..3

    const float* __restrict__ f1bh = f1 + (size_t)b * CHW + (size_t)h * WDIM;
    const float* __restrict__ f2bh = f2 + (size_t)b * CHW + (size_t)h * WDIM;

    const int wl    = lane & 31;
    const int wglob = wt * 32 + wl;
    const int koff  = (lane >> 5) * 8;

    // p-tiles t=0..2 -> tp = wt-2+t; clamp invalid (computed, discarded)
    const int c0 = ((wt - 2 < 0) ? 0 : wt - 2) * 32 + wl;
    const int c1 = ((wt - 1 < 0) ? 0 : wt - 1) * 32 + wl;
    const int c2 = wt * 32 + wl;

    f32x16 acc0 = (f32x16)0.0f, acc1 = (f32x16)0.0f, acc2 = (f32x16)0.0f;

    const float* pB  = f1bh + (size_t)koff * HW + wglob;
    const float* pA0 = f2bh + (size_t)koff * HW + c0;
    const float* pA1 = f2bh + (size_t)koff * HW + c1;
    const float* pA2 = f2bh + (size_t)koff * HW + c2;

    #pragma unroll
    for (int kk = 0; kk < 8; ++kk) {
        const size_t kb = (size_t)(kk * 16) * HW;

        float rb[8], ra0[8], ra1[8], ra2[8];
        #pragma unroll
        for (int j = 0; j < 8; ++j) rb[j]  = pB [kb + (size_t)j * HW];
        #pragma unroll
        for (int j = 0; j < 8; ++j) ra0[j] = pA0[kb + (size_t)j * HW];
        #pragma unroll
        for (int j = 0; j < 8; ++j) ra1[j] = pA1[kb + (size_t)j * HW];
        #pragma unroll
        for (int j = 0; j < 8; ++j) ra2[j] = pA2[kb + (size_t)j * HW];

        bf16x8 fb, fa0, fa1, fa2;
        #pragma unroll
        for (int j = 0; j < 8; ++j) {
            fb[j]  = f2bf(rb[j]);
            fa0[j] = f2bf(ra0[j]);
            fa1[j] = f2bf(ra1[j]);
            fa2[j] = f2bf(ra2[j]);
        }

        acc0 = __builtin_amdgcn_mfma_f32_32x32x16_bf16(fa0, fb, acc0, 0, 0, 0);
        acc1 = __builtin_amdgcn_mfma_f32_32x32x16_bf16(fa1, fb, acc1, 0, 0, 0);
        acc2 = __builtin_amdgcn_mfma_f32_32x32x16_bf16(fa2, fb, acc2, 0, 0, 0);
    }

    // ---- wave-private epilogue: zero strip, scatter band, coalesced nt-store ----

    // phase 1: zero-fill the [64][32] strip (512 f32x4, 8 per lane)
    #pragma unroll
    for (int it = 0; it < 8; ++it)
        reinterpret_cast<f32x4*>(strip)[it * 64 + lane] = (f32x4)0.0f;

    lds_fence();   // WAW: zero-fill (f32x4) must land before scalar scatter

    // phase 2: scatter. D row = (r&3) + 8*(r>>2) + 4*(lane>>5), col = lane&31.
    const int rbase = 4 * (lane >> 5);
    {
        const f32x16* accs[3] = { &acc0, &acc1, &acc2 };
        #pragma unroll
        for (int t = 0; t < 3; ++t) {
            const int tp = wt - 2 + t;
            if (tp >= 0) {
                const f32x16 a = *accs[t];
                #pragma unroll
                for (int r = 0; r < 16; ++r) {
                    const int prow = tp * 32 + (r & 3) + 8 * (r >> 2) + rbase;
                    const int i = wglob - prow;   // disparity
                    if (i >= 0 && i < LVLS)
                        strip[i * 32 + wl] = a[r] * (1.0f / CDIM);
                }
            }
        }
    }

    lds_fence();   // RAW: scalar scatter must land before f32x4 store-loop reads

    // phase 3: store out[b][i][h][wt*32 .. +32). Each iter reads a contiguous
    // 1 KiB LDS span (conflict-free) and writes 8 rows x 128 B.
    const size_t obase = (size_t)b * LVLS * HW + (size_t)h * WDIM + wt * 32;
    #pragma unroll
    for (int it = 0; it < 8; ++it) {
        const int idx = it * 64 + lane;       // 0..511 f32x4s
        const int row = idx >> 3;             // i
        const int w4  = idx & 7;
        const f32x4 v = *reinterpret_cast<const f32x4*>(&strip[row * 32 + w4 * 4]);
        __builtin_nontemporal_store(v, reinterpret_cast<f32x4*>(out + obase + (size_t)row * HW + w4 * 4));
    }
}

extern "C" void kernel_launch(void* const* d_in, const int* in_sizes, int n_in,
                              void* d_out, int out_size, void* d_ws, size_t ws_size,
                              hipStream_t stream) {
    const float* f1 = (const float*)d_in[0];
    const float* f2 = (const float*)d_in[1];
    float* out = (float*)d_out;
    cost_volume_kernel<<<dim3(NWORK), dim3(64), 0, stream>>>(f1, f2, out);
}

// Round 9
// 29.966 us; speedup vs baseline: 1.0812x; 1.0165x over previous
//
#include <hip/hip_runtime.h>
#include <hip/hip_bf16.h>

// Cost volume: cost[b,i,h,w] = mean_c f1[b,c,h,w] * f2[b,c,h,w-i], i in [0,64), 0 if w<i.
// B=4, C=128, H=128, W=256, lvls=64. fp32 in/out, bf16 MFMA compute.
//
// R9: R8's desynchronized wave-per-work-unit structure, but TWO independent
// waves per block (128 thr, 16 KB LDS = 2 private strips) to raise occupancy:
// single-wave blocks were capped by the ~16 workgroup-slots/CU (Occupancy 36%);
// 2-wave blocks hit the LDS limit at 10 blocks/CU -> 20 waves/CU.
// Still ZERO cross-wave barriers: each wave computes its (b,h,wt) unit,
// transposes through its private [64 i][32 w] strip (intra-wave lgkmcnt fences
// only), and nontemporal-stores. Chunked XCD swizzle keeps f2 tile reuse on-XCD.

#define BDIM 4
#define CDIM 128
#define HDIM 128
#define WDIM 256
#define LVLS 64
#define HW   (HDIM * WDIM)          // 32768
#define CHW  (CDIM * HDIM * WDIM)   // 4194304
#define NWORK (BDIM * HDIM * 8)     // 4096 work units
#define NBLK  (NWORK / 2)           // 2048 blocks

typedef short    bf16x8 __attribute__((ext_vector_type(8)));
typedef float    f32x16 __attribute__((ext_vector_type(16)));
typedef float    f32x4  __attribute__((ext_vector_type(4)));

__device__ __forceinline__ short f2bf(float f) {
    __hip_bfloat16 h = __float2bfloat16(f);
    return __builtin_bit_cast(short, h);
}

__device__ __forceinline__ void lds_fence() {
    // order LDS phases within the wave: drain outstanding DS ops and pin the
    // compiler's schedule across the boundary (TBAA can't see the aliasing).
    asm volatile("s_waitcnt lgkmcnt(0)" ::: "memory");
    __builtin_amdgcn_sched_barrier(0);
}

__global__ __launch_bounds__(128, 8) void cost_volume_kernel(
    const float* __restrict__ f1, const float* __restrict__ f2,
    float* __restrict__ out)
{
    __shared__ float strips[2][LVLS * 32];   // 16 KiB: one private strip per wave

    const int tid  = threadIdx.x;
    const int lane = tid & 63;
    const int wv   = tid >> 6;           // wave 0/1 -> independent work units

    // chunked XCD swizzle (2048 blocks, 8 XCDs, 256-block chunks), then 2
    // consecutive work units per block (they share f2 tiles -> L2 locality).
    const int bid  = blockIdx.x;
    const int work = ((bid & 7) * (NBLK / 8) + (bid >> 3)) * 2 + wv;

    const int wt = work & 7;             // w-tile 0..7
    const int h  = (work >> 3) & (HDIM - 1);
    const int b  = work >> 10;           // 0..3

    float* strip = strips[wv];

    const float* __restrict__ f1bh = f1 + (size_t)b * CHW + (size_t)h * WDIM;
    const float* __restrict__ f2bh = f2 + (size_t)b * CHW + (size_t)h * WDIM;

    const int wl    = lane & 31;
    const int wglob = wt * 32 + wl;
    const int koff  = (lane >> 5) * 8;

    // p-tiles t=0..2 -> tp = wt-2+t; clamp invalid (computed, discarded)
    const int c0 = ((wt - 2 < 0) ? 0 : wt - 2) * 32 + wl;
    const int c1 = ((wt - 1 < 0) ? 0 : wt - 1) * 32 + wl;
    const int c2 = wt * 32 + wl;

    f32x16 acc0 = (f32x16)0.0f, acc1 = (f32x16)0.0f, acc2 = (f32x16)0.0f;

    const float* pB  = f1bh + (size_t)koff * HW + wglob;
    const float* pA0 = f2bh + (size_t)koff * HW + c0;
    const float* pA1 = f2bh + (size_t)koff * HW + c1;
    const float* pA2 = f2bh + (size_t)koff * HW + c2;

    #pragma unroll
    for (int kk = 0; kk < 8; ++kk) {
        const size_t kb = (size_t)(kk * 16) * HW;

        float rb[8], ra0[8], ra1[8], ra2[8];
        #pragma unroll
        for (int j = 0; j < 8; ++j) rb[j]  = pB [kb + (size_t)j * HW];
        #pragma unroll
        for (int j = 0; j < 8; ++j) ra0[j] = pA0[kb + (size_t)j * HW];
        #pragma unroll
        for (int j = 0; j < 8; ++j) ra1[j] = pA1[kb + (size_t)j * HW];
        #pragma unroll
        for (int j = 0; j < 8; ++j) ra2[j] = pA2[kb + (size_t)j * HW];

        bf16x8 fb, fa0, fa1, fa2;
        #pragma unroll
        for (int j = 0; j < 8; ++j) {
            fb[j]  = f2bf(rb[j]);
            fa0[j] = f2bf(ra0[j]);
            fa1[j] = f2bf(ra1[j]);
            fa2[j] = f2bf(ra2[j]);
        }

        acc0 = __builtin_amdgcn_mfma_f32_32x32x16_bf16(fa0, fb, acc0, 0, 0, 0);
        acc1 = __builtin_amdgcn_mfma_f32_32x32x16_bf16(fa1, fb, acc1, 0, 0, 0);
        acc2 = __builtin_amdgcn_mfma_f32_32x32x16_bf16(fa2, fb, acc2, 0, 0, 0);
    }

    // ---- wave-private epilogue: zero strip, scatter band, coalesced nt-store ----

    // phase 1: zero-fill the [64][32] strip (512 f32x4, 8 per lane)
    #pragma unroll
    for (int it = 0; it < 8; ++it)
        reinterpret_cast<f32x4*>(strip)[it * 64 + lane] = (f32x4)0.0f;

    lds_fence();   // WAW: zero-fill (f32x4) must land before scalar scatter

    // phase 2: scatter. D row = (r&3) + 8*(r>>2) + 4*(lane>>5), col = lane&31.
    const int rbase = 4 * (lane >> 5);
    {
        const f32x16* accs[3] = { &acc0, &acc1, &acc2 };
        #pragma unroll
        for (int t = 0; t < 3; ++t) {
            const int tp = wt - 2 + t;
            if (tp >= 0) {
                const f32x16 a = *accs[t];
                #pragma unroll
                for (int r = 0; r < 16; ++r) {
                    const int prow = tp * 32 + (r & 3) + 8 * (r >> 2) + rbase;
                    const int i = wglob - prow;   // disparity
                    if (i >= 0 && i < LVLS)
                        strip[i * 32 + wl] = a[r] * (1.0f / CDIM);
                }
            }
        }
    }

    lds_fence();   // RAW: scalar scatter must land before f32x4 store-loop reads

    // phase 3: store out[b][i][h][wt*32 .. +32). Each iter reads a contiguous
    // 1 KiB LDS span (conflict-free) and writes 8 rows x 128 B.
    const size_t obase = (size_t)b * LVLS * HW + (size_t)h * WDIM + wt * 32;
    #pragma unroll
    for (int it = 0; it < 8; ++it) {
        const int idx = it * 64 + lane;       // 0..511 f32x4s
        const int row = idx >> 3;             // i
        const int w4  = idx & 7;
        const f32x4 v = *reinterpret_cast<const f32x4*>(&strip[row * 32 + w4 * 4]);
        __builtin_nontemporal_store(v, reinterpret_cast<f32x4*>(out + obase + (size_t)row * HW + w4 * 4));
    }
}

extern "C" void kernel_launch(void* const* d_in, const int* in_sizes, int n_in,
                              void* d_out, int out_size, void* d_ws, size_t ws_size,
                              hipStream_t stream) {
    const float* f1 = (const float*)d_in[0];
    const float* f2 = (const float*)d_in[1];
    float* out = (float*)d_out;
    cost_volume_kernel<<<dim3(NBLK), dim3(128), 0, stream>>>(f1, f2, out);
}